// Round 2
// baseline (1498.672 us; speedup 1.0000x reference)
//
#include <hip/hip_runtime.h>
#include <math.h>

#define NTOK 6272   // B*H*W = 32*14*14

__device__ __forceinline__ float sigmoidf_(float v){ return 1.0f/(1.0f + expf(-v)); }

// ---------------- gating: logits -> softmax -> top2 -> comb + avg/load sums ----------------
__global__ __launch_bounds__(256) void gate_kernel(
    const float* __restrict__ x, const float* __restrict__ eq,
    const float* __restrict__ temp, float* __restrict__ comb,
    float* __restrict__ avgsum, float* __restrict__ loadsum)
{
  __shared__ float lacc[8];
  if (threadIdx.x < 8) lacc[threadIdx.x] = 0.f;
  __syncthreads();
  int wid = threadIdx.x >> 6, lane = threadIdx.x & 63;
  int m = blockIdx.x*4 + wid;             // token index
  const float* xr = x + (size_t)m*512;
  float a0=0.f,a1=0.f,a2=0.f,a3=0.f;
  #pragma unroll
  for (int j=0;j<8;++j){
    float xv = xr[j*64+lane];
    a0 = fmaf(xv, eq[0*512 + j*64+lane], a0);
    a1 = fmaf(xv, eq[1*512 + j*64+lane], a1);
    a2 = fmaf(xv, eq[2*512 + j*64+lane], a2);
    a3 = fmaf(xv, eq[3*512 + j*64+lane], a3);
  }
  #pragma unroll
  for (int off=32; off; off>>=1){
    a0 += __shfl_xor(a0,off); a1 += __shfl_xor(a1,off);
    a2 += __shfl_xor(a2,off); a3 += __shfl_xor(a3,off);
  }
  if (lane == 0){
    float T = temp[0];
    float l0=a0/T, l1=a1/T, l2=a2/T, l3=a3/T;
    float mx = fmaxf(fmaxf(l0,l1), fmaxf(l2,l3));
    float e0=expf(l0-mx), e1=expf(l1-mx), e2=expf(l2-mx), e3=expf(l3-mx);
    float s = e0+e1+e2+e3;
    float g0=e0/s, g1=e1/s, g2=e2/s, g3=e3/s;
    // top-1 (ties -> lowest index, matches lax.top_k)
    int i1=0; float v1=g0;
    if (g1>v1){v1=g1;i1=1;}
    if (g2>v1){v1=g2;i1=2;}
    if (g3>v1){v1=g3;i1=3;}
    // top-2
    int i2=-1; float v2=-2.f;
    if (i1!=0)          {v2=g0;i2=0;}
    if (i1!=1 && g1>v2) {v2=g1;i2=1;}
    if (i1!=2 && g2>v2) {v2=g2;i2=2;}
    if (i1!=3 && g3>v2) {v2=g3;i2=3;}
    float inv = 1.f/(v1+v2);
    float c0 = (i1==0)? v1*inv : ((i2==0)? v2*inv : 0.f);
    float c1 = (i1==1)? v1*inv : ((i2==1)? v2*inv : 0.f);
    float c2 = (i1==2)? v1*inv : ((i2==2)? v2*inv : 0.f);
    float c3 = (i1==3)? v1*inv : ((i2==3)? v2*inv : 0.f);
    comb[(size_t)m*4+0]=c0; comb[(size_t)m*4+1]=c1;
    comb[(size_t)m*4+2]=c2; comb[(size_t)m*4+3]=c3;
    atomicAdd(&lacc[0], g0); atomicAdd(&lacc[1], g1);
    atomicAdd(&lacc[2], g2); atomicAdd(&lacc[3], g3);
    atomicAdd(&lacc[4+i1], 0.5f);
    atomicAdd(&lacc[4+i2], 0.5f);
  }
  __syncthreads();
  if (threadIdx.x < 4){
    atomicAdd(&avgsum[threadIdx.x],  lacc[threadIdx.x]);
    atomicAdd(&loadsum[threadIdx.x], lacc[4+threadIdx.x]);
  }
}

__global__ void aux_kernel(const float* __restrict__ avgsum,
                           const float* __restrict__ loadsum,
                           float* __restrict__ out_aux)
{
  if (threadIdx.x == 0 && blockIdx.x == 0){
    float s = 0.f;
    #pragma unroll
    for (int e=0;e<4;++e)
      s += (avgsum[e]/(float)NTOK) * (loadsum[e]/(float)NTOK);
    out_aux[0] = 0.01f * (s * 0.25f) * 16.0f;
  }
}

// ---------------- in_proj GEMM: C[6272x1024] = A[6272x512] * W^T (W: 1024x512) ----------------
__global__ __launch_bounds__(256) void gemm_inproj(
    const float* __restrict__ A, const float* __restrict__ Wt, float* __restrict__ C)
{
  __shared__ float As[16][68];
  __shared__ float Bs[16][68];
  int m0 = blockIdx.x*64, n0 = blockIdx.y*64;
  int t = threadIdx.x;
  int lrow = t>>2, lk = (t&3)<<2;
  int tm = t>>4, tn = t&15;
  float acc[4][4] = {};
  const float* Arow = A  + (size_t)(m0+lrow)*512 + lk;
  const float* Brow = Wt + (size_t)(n0+lrow)*512 + lk;
  for (int k0=0; k0<512; k0+=16){
    float4 av = *(const float4*)(Arow + k0);
    float4 bv = *(const float4*)(Brow + k0);
    __syncthreads();
    As[lk+0][lrow]=av.x; As[lk+1][lrow]=av.y; As[lk+2][lrow]=av.z; As[lk+3][lrow]=av.w;
    Bs[lk+0][lrow]=bv.x; Bs[lk+1][lrow]=bv.y; Bs[lk+2][lrow]=bv.z; Bs[lk+3][lrow]=bv.w;
    __syncthreads();
    #pragma unroll
    for (int kk=0; kk<16; ++kk){
      float4 a = *(const float4*)&As[kk][tm<<2];
      float4 b = *(const float4*)&Bs[kk][tn<<2];
      acc[0][0]=fmaf(a.x,b.x,acc[0][0]); acc[0][1]=fmaf(a.x,b.y,acc[0][1]);
      acc[0][2]=fmaf(a.x,b.z,acc[0][2]); acc[0][3]=fmaf(a.x,b.w,acc[0][3]);
      acc[1][0]=fmaf(a.y,b.x,acc[1][0]); acc[1][1]=fmaf(a.y,b.y,acc[1][1]);
      acc[1][2]=fmaf(a.y,b.z,acc[1][2]); acc[1][3]=fmaf(a.y,b.w,acc[1][3]);
      acc[2][0]=fmaf(a.z,b.x,acc[2][0]); acc[2][1]=fmaf(a.z,b.y,acc[2][1]);
      acc[2][2]=fmaf(a.z,b.z,acc[2][2]); acc[2][3]=fmaf(a.z,b.w,acc[2][3]);
      acc[3][0]=fmaf(a.w,b.x,acc[3][0]); acc[3][1]=fmaf(a.w,b.y,acc[3][1]);
      acc[3][2]=fmaf(a.w,b.z,acc[3][2]); acc[3][3]=fmaf(a.w,b.w,acc[3][3]);
    }
  }
  #pragma unroll
  for (int i=0;i<4;++i){
    float4 o = make_float4(acc[i][0],acc[i][1],acc[i][2],acc[i][3]);
    *(float4*)(C + (size_t)(m0+tm*4+i)*1024 + n0 + tn*4) = o;
  }
}

// ---------------- depthwise 3x3 conv + bias + SiLU ----------------
__global__ __launch_bounds__(512) void conv_kernel(
    const float* __restrict__ xz, const float* __restrict__ cw,
    const float* __restrict__ cb, float* __restrict__ xc)
{
  int t = blockIdx.x, b = blockIdx.y, d = threadIdx.x;
  int h = t/14, w = t - h*14;
  float s = cb[d];
  #pragma unroll
  for (int dh=-1; dh<=1; ++dh){
    int hh = h+dh; if ((unsigned)hh >= 14u) continue;
    #pragma unroll
    for (int dw=-1; dw<=1; ++dw){
      int ww = w+dw; if ((unsigned)ww >= 14u) continue;
      s = fmaf(xz[((size_t)(b*196 + hh*14+ww))*1024 + d],
               cw[d*9 + (dh+1)*3 + (dw+1)], s);
    }
  }
  xc[((size_t)(b*196+t))*512 + d] = s * sigmoidf_(s);
}

// ---------------- x_dbl projection: proj[b,t,k*6+c] = dot(xc[b,t,:], xw[k,c,:]) ----------------
__global__ __launch_bounds__(256) void proj_kernel(
    const float* __restrict__ xc, const float* __restrict__ xw, float* __restrict__ proj)
{
  int wid = threadIdx.x>>6, lane = threadIdx.x&63;
  int m = blockIdx.x*4 + wid;
  const float* xr = xc + (size_t)m*512;
  float xv[8];
  #pragma unroll
  for (int j=0;j<8;++j) xv[j] = xr[j*64+lane];
  #pragma unroll
  for (int kc=0;kc<24;++kc){
    const float* wr = xw + (size_t)kc*512;
    float a = 0.f;
    #pragma unroll
    for (int j=0;j<8;++j) a = fmaf(xv[j], wr[j*64+lane], a);
    #pragma unroll
    for (int off=32; off; off>>=1) a += __shfl_xor(a,off);
    if (lane==0) proj[(size_t)m*24 + kc] = a;
  }
}

// ---------------- selective scan, one thread per (b,k,d), atomic merge of 4 directions ----------------
__device__ __forceinline__ int perm_t(int k, int l){
  if (k==0) return l;
  if (k==1) return 195-l;
  if (k==2) return (l%14)*14 + l/14;
  int lr = 195-l; return (lr%14)*14 + lr/14;
}

__global__ __launch_bounds__(256) void scan_kernel(
    const float* __restrict__ xc, const float* __restrict__ proj,
    const float* __restrict__ Alogs, const float* __restrict__ Dsp,
    const float* __restrict__ dtw, const float* __restrict__ dtb,
    float* __restrict__ ycomb)
{
  int g = blockIdx.x*256 + threadIdx.x;   // ((b*4 + k)*512 + d)
  int d = g & 511;
  int bk = g >> 9;
  int k = bk & 3;
  int b = bk >> 2;
  float Ak  = -expf(Alogs[k*512 + d]);
  float Dk  = Dsp[k*512 + d];
  float btk = dtb[k*512 + d];
  const float* wr = dtw + ((size_t)(k*512 + d))*4;
  float w0=wr[0], w1=wr[1], w2=wr[2], w3=wr[3];
  float hst = 0.f;
  const float* xcb = xc + (size_t)b*196*512 + d;
  const float* pb  = proj + (size_t)b*196*24 + k*6;
  float* yb = ycomb + (size_t)b*196*512 + d;

  // software-pipelined: prefetch iteration l+1's loads before computing l
  int t = perm_t(k, 0);
  float xval = xcb[(size_t)t*512];
  const float* pp = pb + (size_t)t*24;
  float p0=pp[0], p1=pp[1], p2=pp[2], p3=pp[3], Bsv=pp[4], Csv=pp[5];

  for (int l=0; l<196; ++l){
    int tn_ = (l < 195) ? perm_t(k, l+1) : t;
    float xval_n = xcb[(size_t)tn_*512];
    const float* ppn = pb + (size_t)tn_*24;
    float q0=ppn[0], q1=ppn[1], q2=ppn[2], q3=ppn[3], Bn_=ppn[4], Cn_=ppn[5];

    float dtraw = btk + w0*p0 + w1*p1 + w2*p2 + w3*p3;
    float dt = (dtraw > 0.f) ? (dtraw + log1pf(expf(-dtraw))) : log1pf(expf(dtraw));
    float dA = expf(dt*Ak);
    hst = fmaf(dA, hst, dt*xval*Bsv);
    float y = fmaf(hst, Csv, xval*Dk);
    atomicAdd(&yb[(size_t)t*512], y);

    t = tn_; xval = xval_n;
    p0=q0; p1=q1; p2=q2; p3=q3; Bsv=Bn_; Csv=Cn_;
  }
}

// ---------------- LayerNorm + SiLU(z) gate + comb mix + token-mean accumulate ----------------
__global__ __launch_bounds__(512) void final_kernel(
    const float* __restrict__ ycomb, const float* __restrict__ xz,
    const float* __restrict__ comb, const float* __restrict__ nw,
    const float* __restrict__ nb, float* __restrict__ out, int e)
{
  int b = blockIdx.x;
  int t0 = blockIdx.y*28;
  int d = threadIdx.x;
  int wid = d>>6, lane = d&63;
  __shared__ float red[16];
  float wv = nw[d], bv = nb[d];
  float acc = 0.f;
  for (int ti=0; ti<28; ++ti){
    int t = t0 + ti;
    float v = ycomb[((size_t)(b*196+t))*512 + d];
    float s=v, q=v*v;
    #pragma unroll
    for (int off=32; off; off>>=1){ s += __shfl_xor(s,off); q += __shfl_xor(q,off); }
    if (lane==0){ red[wid]=s; red[8+wid]=q; }
    __syncthreads();
    float tot=0.f, qt=0.f;
    #pragma unroll
    for (int i=0;i<8;++i){ tot+=red[i]; qt+=red[8+i]; }
    float mu  = tot*(1.f/512.f);
    float var = fmaf(qt, (1.f/512.f), -mu*mu);
    float rs  = rsqrtf(var + 1e-5f);
    float ln  = (v-mu)*rs*wv + bv;
    float z   = xz[((size_t)(b*196+t))*1024 + 512 + d];
    float sz  = z*sigmoidf_(z);
    acc = fmaf(comb[(size_t)(b*196+t)*4 + e]*ln, sz, acc);
    __syncthreads();
  }
  atomicAdd(&out[(size_t)b*512+d], acc*(1.f/196.f));
}

extern "C" void kernel_launch(void* const* d_in, const int* in_sizes, int n_in,
                              void* d_out, int out_size, void* d_ws, size_t ws_size,
                              hipStream_t stream)
{
  const float* x    = (const float*)d_in[0];
  const float* eq   = (const float*)d_in[1];
  const float* temp = (const float*)d_in[2];
  const float* ipw  = (const float*)d_in[3];
  const float* cw   = (const float*)d_in[4];
  const float* cb   = (const float*)d_in[5];
  const float* xpw  = (const float*)d_in[6];
  const float* dtw  = (const float*)d_in[7];
  const float* dtb  = (const float*)d_in[8];
  const float* alog = (const float*)d_in[9];
  const float* dsp  = (const float*)d_in[10];
  const float* nw   = (const float*)d_in[11];
  const float* nb   = (const float*)d_in[12];
  float* out = (float*)d_out;

  float* ws      = (float*)d_ws;
  float* comb    = ws;                    // 25088
  float* avgsum  = ws + 25088;            // 4
  float* loadsum = ws + 25092;            // 4
  float* xz      = ws + 25600;            // 6,422,528
  float* xcact   = xz + 6422528;          // 3,211,264
  float* proj    = xcact + 3211264;       // 150,528
  float* ycomb   = proj + 150528;         // 3,211,264   (total ~52.1 MB)

  (void)hipMemsetAsync(avgsum, 0, 8*sizeof(float), stream);
  (void)hipMemsetAsync(d_out, 0, (size_t)out_size*sizeof(float), stream);

  gate_kernel<<<dim3(1568), dim3(256), 0, stream>>>(x, eq, temp, comb, avgsum, loadsum);
  aux_kernel<<<dim3(1), dim3(64), 0, stream>>>(avgsum, loadsum, out + 16384);

  for (int e=0; e<4; ++e){
    gemm_inproj<<<dim3(98,16), dim3(256), 0, stream>>>(x, ipw + (size_t)e*1024*512, xz);
    conv_kernel<<<dim3(196,32), dim3(512), 0, stream>>>(xz, cw + (size_t)e*512*9, cb + (size_t)e*512, xcact);
    proj_kernel<<<dim3(1568), dim3(256), 0, stream>>>(xcact, xpw + (size_t)e*24*512, proj);
    (void)hipMemsetAsync(ycomb, 0, (size_t)NTOK*512*sizeof(float), stream);
    scan_kernel<<<dim3(256), dim3(256), 0, stream>>>(xcact, proj,
        alog + (size_t)e*2048, dsp + (size_t)e*2048,
        dtw + (size_t)e*4*512*4, dtb + (size_t)e*2048, ycomb);
    final_kernel<<<dim3(32,7), dim3(512), 0, stream>>>(ycomb, xz, comb, nw + e*512, nb + e*512, out, e);
  }
}

// Round 3
// 846.341 us; speedup vs baseline: 1.7708x; 1.7708x over previous
//
#include <hip/hip_runtime.h>
#include <math.h>

#define NTOK 6272   // B*H*W = 32*14*14

typedef __attribute__((ext_vector_type(8))) short short8;
typedef __attribute__((ext_vector_type(8))) unsigned short ushort8;
typedef __attribute__((ext_vector_type(4))) float f32x4;

__device__ __forceinline__ float sigmoidf_(float v){ return 1.0f/(1.0f + expf(-v)); }

// f32 -> bf16 round-to-nearest-even
__device__ __forceinline__ unsigned short f2b(float f){
  union { float f; unsigned u; } v; v.f = f;
  unsigned r = (v.u + 0x7fffu + ((v.u>>16)&1u)) >> 16;
  return (unsigned short)r;
}

// ---------------- gating: logits -> softmax -> top2 -> comb + avg/load sums ----------------
__global__ __launch_bounds__(256) void gate_kernel(
    const float* __restrict__ x, const float* __restrict__ eq,
    const float* __restrict__ temp, float* __restrict__ comb,
    float* __restrict__ avgsum, float* __restrict__ loadsum)
{
  __shared__ float lacc[8];
  if (threadIdx.x < 8) lacc[threadIdx.x] = 0.f;
  __syncthreads();
  int wid = threadIdx.x >> 6, lane = threadIdx.x & 63;
  int m = blockIdx.x*4 + wid;             // token index
  const float* xr = x + (size_t)m*512;
  float a0=0.f,a1=0.f,a2=0.f,a3=0.f;
  #pragma unroll
  for (int j=0;j<8;++j){
    float xv = xr[j*64+lane];
    a0 = fmaf(xv, eq[0*512 + j*64+lane], a0);
    a1 = fmaf(xv, eq[1*512 + j*64+lane], a1);
    a2 = fmaf(xv, eq[2*512 + j*64+lane], a2);
    a3 = fmaf(xv, eq[3*512 + j*64+lane], a3);
  }
  #pragma unroll
  for (int off=32; off; off>>=1){
    a0 += __shfl_xor(a0,off); a1 += __shfl_xor(a1,off);
    a2 += __shfl_xor(a2,off); a3 += __shfl_xor(a3,off);
  }
  if (lane == 0){
    float T = temp[0];
    float l0=a0/T, l1=a1/T, l2=a2/T, l3=a3/T;
    float mx = fmaxf(fmaxf(l0,l1), fmaxf(l2,l3));
    float e0=expf(l0-mx), e1=expf(l1-mx), e2=expf(l2-mx), e3=expf(l3-mx);
    float s = e0+e1+e2+e3;
    float g0=e0/s, g1=e1/s, g2=e2/s, g3=e3/s;
    int i1=0; float v1=g0;
    if (g1>v1){v1=g1;i1=1;}
    if (g2>v1){v1=g2;i1=2;}
    if (g3>v1){v1=g3;i1=3;}
    int i2=-1; float v2=-2.f;
    if (i1!=0)          {v2=g0;i2=0;}
    if (i1!=1 && g1>v2) {v2=g1;i2=1;}
    if (i1!=2 && g2>v2) {v2=g2;i2=2;}
    if (i1!=3 && g3>v2) {v2=g3;i2=3;}
    float inv = 1.f/(v1+v2);
    float c0 = (i1==0)? v1*inv : ((i2==0)? v2*inv : 0.f);
    float c1 = (i1==1)? v1*inv : ((i2==1)? v2*inv : 0.f);
    float c2 = (i1==2)? v1*inv : ((i2==2)? v2*inv : 0.f);
    float c3 = (i1==3)? v1*inv : ((i2==3)? v2*inv : 0.f);
    comb[(size_t)m*4+0]=c0; comb[(size_t)m*4+1]=c1;
    comb[(size_t)m*4+2]=c2; comb[(size_t)m*4+3]=c3;
    atomicAdd(&lacc[0], g0); atomicAdd(&lacc[1], g1);
    atomicAdd(&lacc[2], g2); atomicAdd(&lacc[3], g3);
    atomicAdd(&lacc[4+i1], 0.5f);
    atomicAdd(&lacc[4+i2], 0.5f);
  }
  __syncthreads();
  if (threadIdx.x < 4){
    atomicAdd(&avgsum[threadIdx.x],  lacc[threadIdx.x]);
    atomicAdd(&loadsum[threadIdx.x], lacc[4+threadIdx.x]);
  }
}

__global__ void aux_kernel(const float* __restrict__ avgsum,
                           const float* __restrict__ loadsum,
                           float* __restrict__ out_aux)
{
  if (threadIdx.x == 0 && blockIdx.x == 0){
    float s = 0.f;
    #pragma unroll
    for (int e=0;e<4;++e)
      s += (avgsum[e]/(float)NTOK) * (loadsum[e]/(float)NTOK);
    out_aux[0] = 0.01f * (s * 0.25f) * 16.0f;
  }
}

// ---------------- in_proj GEMM (bf16 MFMA): C[e][6272x1024] = A[6272x512] * W_e^T ----------------
// 64x64 tile, 4 waves (each 32x32 = 2x2 16x16x32 MFMA tiles), reg-staged f32->bf16.
__global__ __launch_bounds__(256) void gemm_mfma(
    const float* __restrict__ A, const float* __restrict__ W,
    float* __restrict__ C, size_t wStride, size_t cStride)
{
  // stride 56 ushort = 112B: multiple of 16B (aligned b128), 112/4=28 -> <=2-way bank conflict
  __shared__ unsigned short As[64][56];
  __shared__ unsigned short Bs[64][56];
  const float* We = W + (size_t)blockIdx.z*wStride;
  float* Ce = C + (size_t)blockIdx.z*cStride;
  int m0 = blockIdx.x*64, n0 = blockIdx.y*64;
  int t = threadIdx.x;
  int srow = t>>2, scol = (t&3)*8;       // staging: each thread 8 consecutive k
  int w = t>>6, lane = t&63;
  int wr = (w>>1)*32, wc = (w&1)*32;     // wave's 32x32 sub-tile
  int fr = lane&15, fk = (lane>>4)*8;    // fragment row/col and k-offset
  f32x4 acc00={0.f,0.f,0.f,0.f}, acc01={0.f,0.f,0.f,0.f};
  f32x4 acc10={0.f,0.f,0.f,0.f}, acc11={0.f,0.f,0.f,0.f};
  const float* ap = A  + (size_t)(m0+srow)*512 + scol;
  const float* bp = We + (size_t)(n0+srow)*512 + scol;
  for (int k0=0; k0<512; k0+=32){
    float4 av0 = *(const float4*)(ap+k0);
    float4 av1 = *(const float4*)(ap+k0+4);
    float4 bv0 = *(const float4*)(bp+k0);
    float4 bv1 = *(const float4*)(bp+k0+4);
    ushort8 va, vb;
    va[0]=f2b(av0.x); va[1]=f2b(av0.y); va[2]=f2b(av0.z); va[3]=f2b(av0.w);
    va[4]=f2b(av1.x); va[5]=f2b(av1.y); va[6]=f2b(av1.z); va[7]=f2b(av1.w);
    vb[0]=f2b(bv0.x); vb[1]=f2b(bv0.y); vb[2]=f2b(bv0.z); vb[3]=f2b(bv0.w);
    vb[4]=f2b(bv1.x); vb[5]=f2b(bv1.y); vb[6]=f2b(bv1.z); vb[7]=f2b(bv1.w);
    __syncthreads();
    *(ushort8*)&As[srow][scol] = va;
    *(ushort8*)&Bs[srow][scol] = vb;
    __syncthreads();
    short8 a0 = *(short8*)&As[wr+fr][fk];
    short8 a1 = *(short8*)&As[wr+16+fr][fk];
    short8 b0 = *(short8*)&Bs[wc+fr][fk];
    short8 b1 = *(short8*)&Bs[wc+16+fr][fk];
    acc00 = __builtin_amdgcn_mfma_f32_16x16x32_bf16(a0,b0,acc00,0,0,0);
    acc01 = __builtin_amdgcn_mfma_f32_16x16x32_bf16(a0,b1,acc01,0,0,0);
    acc10 = __builtin_amdgcn_mfma_f32_16x16x32_bf16(a1,b0,acc10,0,0,0);
    acc11 = __builtin_amdgcn_mfma_f32_16x16x32_bf16(a1,b1,acc11,0,0,0);
  }
  int orow = (lane>>4)*4;   // C/D: col=lane&15, row=(lane>>4)*4+reg  [m89-verified]
  #pragma unroll
  for (int r=0;r<4;++r){
    Ce[(size_t)(m0+wr+orow+r)*1024    + n0+wc+fr]    = acc00[r];
    Ce[(size_t)(m0+wr+orow+r)*1024    + n0+wc+16+fr] = acc01[r];
    Ce[(size_t)(m0+wr+16+orow+r)*1024 + n0+wc+fr]    = acc10[r];
    Ce[(size_t)(m0+wr+16+orow+r)*1024 + n0+wc+16+fr] = acc11[r];
  }
}

// ---------------- depthwise 3x3 conv + bias + SiLU (expert = blockIdx.z) ----------------
__global__ __launch_bounds__(512) void conv_kernel(
    const float* __restrict__ xz, const float* __restrict__ cw,
    const float* __restrict__ cb, float* __restrict__ xc,
    size_t xzS, size_t xcS)
{
  int e = blockIdx.z;
  const float* xze = xz + (size_t)e*xzS;
  const float* cwe = cw + (size_t)e*4608;
  const float* cbe = cb + (size_t)e*512;
  float* xce = xc + (size_t)e*xcS;
  int t = blockIdx.x, b = blockIdx.y, d = threadIdx.x;
  int h = t/14, w = t - h*14;
  float s = cbe[d];
  #pragma unroll
  for (int dh=-1; dh<=1; ++dh){
    int hh = h+dh; if ((unsigned)hh >= 14u) continue;
    #pragma unroll
    for (int dw=-1; dw<=1; ++dw){
      int ww = w+dw; if ((unsigned)ww >= 14u) continue;
      s = fmaf(xze[((size_t)(b*196 + hh*14+ww))*1024 + d],
               cwe[d*9 + (dh+1)*3 + (dw+1)], s);
    }
  }
  xce[((size_t)(b*196+t))*512 + d] = s * sigmoidf_(s);
}

// ---------------- x_dbl projection (expert = blockIdx.y) ----------------
__global__ __launch_bounds__(256) void proj_kernel(
    const float* __restrict__ xc, const float* __restrict__ xw, float* __restrict__ proj,
    size_t xcS, size_t prS)
{
  int e = blockIdx.y;
  const float* xce = xc + (size_t)e*xcS;
  const float* xwe = xw + (size_t)e*12288;
  float* pre = proj + (size_t)e*prS;
  int wid = threadIdx.x>>6, lane = threadIdx.x&63;
  int m = blockIdx.x*4 + wid;
  const float* xr = xce + (size_t)m*512;
  float xv[8];
  #pragma unroll
  for (int j=0;j<8;++j) xv[j] = xr[j*64+lane];
  #pragma unroll
  for (int kc=0;kc<24;++kc){
    const float* wr = xwe + (size_t)kc*512;
    float a = 0.f;
    #pragma unroll
    for (int j=0;j<8;++j) a = fmaf(xv[j], wr[j*64+lane], a);
    #pragma unroll
    for (int off=32; off; off>>=1) a += __shfl_xor(a,off);
    if (lane==0) pre[(size_t)m*24 + kc] = a;
  }
}

// ---------------- selective scan, thread per (e,b,k,d), atomic merge of 4 directions ----------------
__device__ __forceinline__ int perm_t(int k, int l){
  if (k==0) return l;
  if (k==1) return 195-l;
  if (k==2) return (l%14)*14 + l/14;
  int lr = 195-l; return (lr%14)*14 + lr/14;
}

__global__ __launch_bounds__(256) void scan_kernel(
    const float* __restrict__ xc, const float* __restrict__ proj,
    const float* __restrict__ Alogs, const float* __restrict__ Dsp,
    const float* __restrict__ dtw, const float* __restrict__ dtb,
    float* __restrict__ ycomb,
    size_t xcS, size_t prS, size_t ycS)
{
  int g = blockIdx.x*256 + threadIdx.x;
  int e  = g >> 16;                      // 65536 threads per expert
  int ge = g & 65535;
  int d = ge & 511;
  int k = (ge >> 9) & 3;
  int b = ge >> 11;
  const float* xce = xc + (size_t)e*xcS;
  const float* pre = proj + (size_t)e*prS;
  float* yce = ycomb + (size_t)e*ycS;
  int eo = e*2048;
  float Ak  = -expf(Alogs[eo + k*512 + d]);
  float Dk  = Dsp[eo + k*512 + d];
  float btk = dtb[eo + k*512 + d];
  const float* wr = dtw + (size_t)e*8192 + ((size_t)(k*512 + d))*4;
  float w0=wr[0], w1=wr[1], w2=wr[2], w3=wr[3];
  float hst = 0.f;
  const float* xcb = xce + (size_t)b*196*512 + d;
  const float* pb  = pre + (size_t)b*196*24 + k*6;
  float* yb = yce + (size_t)b*196*512 + d;

  // software-pipelined: prefetch iteration l+1's loads before computing l
  int t = perm_t(k, 0);
  float xval = xcb[(size_t)t*512];
  const float* pp = pb + (size_t)t*24;
  float p0=pp[0], p1=pp[1], p2=pp[2], p3=pp[3], Bsv=pp[4], Csv=pp[5];

  for (int l=0; l<196; ++l){
    int tn_ = (l < 195) ? perm_t(k, l+1) : t;
    float xval_n = xcb[(size_t)tn_*512];
    const float* ppn = pb + (size_t)tn_*24;
    float q0=ppn[0], q1=ppn[1], q2=ppn[2], q3=ppn[3], Bn_=ppn[4], Cn_=ppn[5];

    float dtraw = btk + w0*p0 + w1*p1 + w2*p2 + w3*p3;
    float dt = (dtraw > 0.f) ? (dtraw + log1pf(expf(-dtraw))) : log1pf(expf(dtraw));
    float dA = expf(dt*Ak);
    hst = fmaf(dA, hst, dt*xval*Bsv);
    float y = fmaf(hst, Csv, xval*Dk);
    atomicAdd(&yb[(size_t)t*512], y);

    t = tn_; xval = xval_n;
    p0=q0; p1=q1; p2=q2; p3=q3; Bsv=Bn_; Csv=Cn_;
  }
}

// ---------------- LayerNorm + SiLU(z) gate + comb mix + token-mean accumulate ----------------
template<int NEXP>
__global__ __launch_bounds__(512) void final_kernel(
    const float* __restrict__ ycomb, size_t ycS,
    const float* __restrict__ xz, size_t xzS,
    const float* __restrict__ comb, const float* __restrict__ nw,
    const float* __restrict__ nb, float* __restrict__ out, int e0)
{
  int b = blockIdx.x;
  int t0 = blockIdx.y*28;
  int d = threadIdx.x;
  int wid = d>>6, lane = d&63;
  __shared__ float red[16];
  float wv[NEXP], bv[NEXP];
  #pragma unroll
  for (int i=0;i<NEXP;++i){ wv[i]=nw[(size_t)(e0+i)*512+d]; bv[i]=nb[(size_t)(e0+i)*512+d]; }
  float acc = 0.f;
  for (int ti=0; ti<28; ++ti){
    size_t tok = (size_t)(b*196 + t0 + ti);
    #pragma unroll
    for (int i=0;i<NEXP;++i){
      float v = ycomb[(size_t)i*ycS + tok*512 + d];
      float s=v, q=v*v;
      #pragma unroll
      for (int off=32; off; off>>=1){ s += __shfl_xor(s,off); q += __shfl_xor(q,off); }
      if (lane==0){ red[wid]=s; red[8+wid]=q; }
      __syncthreads();
      float tot=0.f, qt=0.f;
      #pragma unroll
      for (int j=0;j<8;++j){ tot+=red[j]; qt+=red[8+j]; }
      float mu  = tot*(1.f/512.f);
      float var = fmaf(qt, (1.f/512.f), -mu*mu);
      float rs  = rsqrtf(var + 1e-5f);
      float ln  = (v-mu)*rs*wv[i] + bv[i];
      float z   = xz[(size_t)i*xzS + tok*1024 + 512 + d];
      acc = fmaf(comb[tok*4 + e0 + i]*ln, z*sigmoidf_(z), acc);
      __syncthreads();
    }
  }
  atomicAdd(&out[(size_t)b*512+d], acc*(1.f/196.f));
}

extern "C" void kernel_launch(void* const* d_in, const int* in_sizes, int n_in,
                              void* d_out, int out_size, void* d_ws, size_t ws_size,
                              hipStream_t stream)
{
  const float* x    = (const float*)d_in[0];
  const float* eq   = (const float*)d_in[1];
  const float* temp = (const float*)d_in[2];
  const float* ipw  = (const float*)d_in[3];
  const float* cw   = (const float*)d_in[4];
  const float* cb   = (const float*)d_in[5];
  const float* xpw  = (const float*)d_in[6];
  const float* dtw  = (const float*)d_in[7];
  const float* dtb  = (const float*)d_in[8];
  const float* alog = (const float*)d_in[9];
  const float* dsp  = (const float*)d_in[10];
  const float* nw   = (const float*)d_in[11];
  const float* nb   = (const float*)d_in[12];
  float* out = (float*)d_out;

  float* ws      = (float*)d_ws;
  float* comb    = ws;                    // 25088
  float* avgsum  = ws + 25088;            // 4
  float* loadsum = ws + 25092;            // 4

  (void)hipMemsetAsync(avgsum, 0, 8*sizeof(float), stream);
  (void)hipMemsetAsync(d_out, 0, (size_t)out_size*sizeof(float), stream);

  gate_kernel<<<dim3(1568), dim3(256), 0, stream>>>(x, eq, temp, comb, avgsum, loadsum);
  aux_kernel<<<dim3(1), dim3(64), 0, stream>>>(avgsum, loadsum, out + 16384);

  const bool batched = (ws_size >= 52007936ull * sizeof(float));  // ~208 MB

  if (batched){
    float* xz = ws + 25600;               // 4 x 6,422,528
    float* xc = xz + 25690112;            // 4 x 3,211,264
    float* pj = xc + 12845056;            // 4 x   150,528
    float* yc = pj + 602112;              // 4 x 3,211,264
    gemm_mfma<<<dim3(98,16,4), dim3(256), 0, stream>>>(x, ipw, xz, 524288, 6422528);
    conv_kernel<<<dim3(196,32,4), dim3(512), 0, stream>>>(xz, cw, cb, xc, 6422528, 3211264);
    proj_kernel<<<dim3(1568,4), dim3(256), 0, stream>>>(xc, xpw, pj, 3211264, 150528);
    (void)hipMemsetAsync(yc, 0, 12845056ull*sizeof(float), stream);
    scan_kernel<<<dim3(1024), dim3(256), 0, stream>>>(xc, pj, alog, dsp, dtw, dtb, yc,
                                                      3211264, 150528, 3211264);
    final_kernel<4><<<dim3(32,7), dim3(512), 0, stream>>>(yc, 3211264, xz, 6422528,
                                                          comb, nw, nb, out, 0);
  } else {
    float* xz = ws + 25600;               // 6,422,528
    float* xc = xz + 6422528;             // 3,211,264
    float* pj = xc + 3211264;             //   150,528
    float* yc = pj + 150528;              // 3,211,264
    for (int e=0; e<4; ++e){
      gemm_mfma<<<dim3(98,16,1), dim3(256), 0, stream>>>(x, ipw + (size_t)e*524288, xz, 0, 0);
      conv_kernel<<<dim3(196,32,1), dim3(512), 0, stream>>>(xz, cw + (size_t)e*4608 - (size_t)0,
                                                            cb + (size_t)e*512 - (size_t)0, xc, 0, 0);
      proj_kernel<<<dim3(1568,1), dim3(256), 0, stream>>>(xc, xpw + (size_t)e*12288, pj, 0, 0);
      (void)hipMemsetAsync(yc, 0, 3211264ull*sizeof(float), stream);
      scan_kernel<<<dim3(256), dim3(256), 0, stream>>>(xc, pj,
          alog + (size_t)e*2048, dsp + (size_t)e*2048,
          dtw + (size_t)e*8192, dtb + (size_t)e*2048, yc, 0, 0, 0);
      final_kernel<1><<<dim3(32,7), dim3(512), 0, stream>>>(yc, 0, xz, 0, comb, nw, nb, out, e);
    }
  }
}

// Round 6
// 600.558 us; speedup vs baseline: 2.4955x; 1.4093x over previous
//
#include <hip/hip_runtime.h>
#include <math.h>

#define NTOK 6272   // B*H*W = 32*14*14

typedef __attribute__((ext_vector_type(8))) short short8;
typedef __attribute__((ext_vector_type(8))) unsigned short ushort8;
typedef __attribute__((ext_vector_type(4))) float f32x4;

__device__ __forceinline__ float sigmoidf_(float v){ return 1.0f/(1.0f + expf(-v)); }

// f32 -> bf16 round-to-nearest-even
__device__ __forceinline__ unsigned short f2b(float f){
  union { float f; unsigned u; } v; v.f = f;
  unsigned r = (v.u + 0x7fffu + ((v.u>>16)&1u)) >> 16;
  return (unsigned short)r;
}

// ---------------- f32 -> bf16 bulk convert (grid-stride, vectorized) ----------------
__global__ __launch_bounds__(256) void cvt_bf16_kernel(
    const float* __restrict__ src, unsigned short* __restrict__ dst, int n8)
{
  int i = blockIdx.x*256 + threadIdx.x;
  int stride = gridDim.x*256;
  for (; i < n8; i += stride){
    float4 a = *(const float4*)(src + (size_t)i*8);
    float4 b = *(const float4*)(src + (size_t)i*8 + 4);
    ushort8 o;
    o[0]=f2b(a.x); o[1]=f2b(a.y); o[2]=f2b(a.z); o[3]=f2b(a.w);
    o[4]=f2b(b.x); o[5]=f2b(b.y); o[6]=f2b(b.z); o[7]=f2b(b.w);
    *(ushort8*)(dst + (size_t)i*8) = o;
  }
}

// ---------------- gating: logits -> softmax -> top2 -> comb + avg/load sums ----------------
__global__ __launch_bounds__(256) void gate_kernel(
    const float* __restrict__ x, const float* __restrict__ eq,
    const float* __restrict__ temp, float* __restrict__ comb,
    float* __restrict__ avgsum, float* __restrict__ loadsum)
{
  __shared__ float lacc[8];
  if (threadIdx.x < 8) lacc[threadIdx.x] = 0.f;
  __syncthreads();
  int wid = threadIdx.x >> 6, lane = threadIdx.x & 63;
  int m = blockIdx.x*4 + wid;             // token index
  const float* xr = x + (size_t)m*512;
  float a0=0.f,a1=0.f,a2=0.f,a3=0.f;
  #pragma unroll
  for (int j=0;j<8;++j){
    float xv = xr[j*64+lane];
    a0 = fmaf(xv, eq[0*512 + j*64+lane], a0);
    a1 = fmaf(xv, eq[1*512 + j*64+lane], a1);
    a2 = fmaf(xv, eq[2*512 + j*64+lane], a2);
    a3 = fmaf(xv, eq[3*512 + j*64+lane], a3);
  }
  #pragma unroll
  for (int off=32; off; off>>=1){
    a0 += __shfl_xor(a0,off); a1 += __shfl_xor(a1,off);
    a2 += __shfl_xor(a2,off); a3 += __shfl_xor(a3,off);
  }
  if (lane == 0){
    float T = temp[0];
    float l0=a0/T, l1=a1/T, l2=a2/T, l3=a3/T;
    float mx = fmaxf(fmaxf(l0,l1), fmaxf(l2,l3));
    float e0=expf(l0-mx), e1=expf(l1-mx), e2=expf(l2-mx), e3=expf(l3-mx);
    float s = e0+e1+e2+e3;
    float g0=e0/s, g1=e1/s, g2=e2/s, g3=e3/s;
    int i1=0; float v1=g0;
    if (g1>v1){v1=g1;i1=1;}
    if (g2>v1){v1=g2;i1=2;}
    if (g3>v1){v1=g3;i1=3;}
    int i2=-1; float v2=-2.f;
    if (i1!=0)          {v2=g0;i2=0;}
    if (i1!=1 && g1>v2) {v2=g1;i2=1;}
    if (i1!=2 && g2>v2) {v2=g2;i2=2;}
    if (i1!=3 && g3>v2) {v2=g3;i2=3;}
    float inv = 1.f/(v1+v2);
    float c0 = (i1==0)? v1*inv : ((i2==0)? v2*inv : 0.f);
    float c1 = (i1==1)? v1*inv : ((i2==1)? v2*inv : 0.f);
    float c2 = (i1==2)? v1*inv : ((i2==2)? v2*inv : 0.f);
    float c3 = (i1==3)? v1*inv : ((i2==3)? v2*inv : 0.f);
    comb[(size_t)m*4+0]=c0; comb[(size_t)m*4+1]=c1;
    comb[(size_t)m*4+2]=c2; comb[(size_t)m*4+3]=c3;
    atomicAdd(&lacc[0], g0); atomicAdd(&lacc[1], g1);
    atomicAdd(&lacc[2], g2); atomicAdd(&lacc[3], g3);
    atomicAdd(&lacc[4+i1], 0.5f);
    atomicAdd(&lacc[4+i2], 0.5f);
  }
  __syncthreads();
  if (threadIdx.x < 4){
    atomicAdd(&avgsum[threadIdx.x],  lacc[threadIdx.x]);
    atomicAdd(&loadsum[threadIdx.x], lacc[4+threadIdx.x]);
  }
}

__global__ void aux_kernel(const float* __restrict__ avgsum,
                           const float* __restrict__ loadsum,
                           float* __restrict__ out_aux)
{
  if (threadIdx.x == 0 && blockIdx.x == 0){
    float s = 0.f;
    #pragma unroll
    for (int e=0;e<4;++e)
      s += (avgsum[e]/(float)NTOK) * (loadsum[e]/(float)NTOK);
    out_aux[0] = 0.01f * (s * 0.25f) * 16.0f;
  }
}

// ---------------- in_proj GEMM, bf16 pre-converted inputs (tier 1) ----------------
// C[e][6272x1024] = A[6272x512] * W_e^T ; A,W already bf16.
__global__ __launch_bounds__(256) void gemm_bf16(
    const unsigned short* __restrict__ A, const unsigned short* __restrict__ W,
    float* __restrict__ C)
{
  __shared__ unsigned short As[64][56];
  __shared__ unsigned short Bs[64][56];
  const unsigned short* We = W + (size_t)blockIdx.z*524288;
  float* Ce = C + (size_t)blockIdx.z*6422528;
  int m0 = blockIdx.x*64, n0 = blockIdx.y*64;
  int t = threadIdx.x;
  int srow = t>>2, scol = (t&3)*8;
  int w = t>>6, lane = t&63;
  int wr = (w>>1)*32, wc = (w&1)*32;
  int fr = lane&15, fk = (lane>>4)*8;
  f32x4 acc00={0.f,0.f,0.f,0.f}, acc01={0.f,0.f,0.f,0.f};
  f32x4 acc10={0.f,0.f,0.f,0.f}, acc11={0.f,0.f,0.f,0.f};
  const unsigned short* ap = A  + (size_t)(m0+srow)*512 + scol;
  const unsigned short* bp = We + (size_t)(n0+srow)*512 + scol;
  for (int k0=0; k0<512; k0+=32){
    ushort8 va = *(const ushort8*)(ap+k0);
    ushort8 vb = *(const ushort8*)(bp+k0);
    __syncthreads();
    *(ushort8*)&As[srow][scol] = va;
    *(ushort8*)&Bs[srow][scol] = vb;
    __syncthreads();
    short8 a0 = *(short8*)&As[wr+fr][fk];
    short8 a1 = *(short8*)&As[wr+16+fr][fk];
    short8 b0 = *(short8*)&Bs[wc+fr][fk];
    short8 b1 = *(short8*)&Bs[wc+16+fr][fk];
    acc00 = __builtin_amdgcn_mfma_f32_16x16x32_bf16(a0,b0,acc00,0,0,0);
    acc01 = __builtin_amdgcn_mfma_f32_16x16x32_bf16(a0,b1,acc01,0,0,0);
    acc10 = __builtin_amdgcn_mfma_f32_16x16x32_bf16(a1,b0,acc10,0,0,0);
    acc11 = __builtin_amdgcn_mfma_f32_16x16x32_bf16(a1,b1,acc11,0,0,0);
  }
  int orow = (lane>>4)*4;   // C/D: col=lane&15, row=(lane>>4)*4+reg  [m89-verified]
  #pragma unroll
  for (int r=0;r<4;++r){
    Ce[(size_t)(m0+wr+orow+r)*1024    + n0+wc+fr]    = acc00[r];
    Ce[(size_t)(m0+wr+orow+r)*1024    + n0+wc+16+fr] = acc01[r];
    Ce[(size_t)(m0+wr+16+orow+r)*1024 + n0+wc+fr]    = acc10[r];
    Ce[(size_t)(m0+wr+16+orow+r)*1024 + n0+wc+16+fr] = acc11[r];
  }
}

// ---------------- in_proj GEMM, in-loop f32->bf16 (tier 2/3 fallback) ----------------
__global__ __launch_bounds__(256) void gemm_mfma(
    const float* __restrict__ A, const float* __restrict__ W,
    float* __restrict__ C, size_t wStride, size_t cStride)
{
  __shared__ unsigned short As[64][56];
  __shared__ unsigned short Bs[64][56];
  const float* We = W + (size_t)blockIdx.z*wStride;
  float* Ce = C + (size_t)blockIdx.z*cStride;
  int m0 = blockIdx.x*64, n0 = blockIdx.y*64;
  int t = threadIdx.x;
  int srow = t>>2, scol = (t&3)*8;
  int w = t>>6, lane = t&63;
  int wr = (w>>1)*32, wc = (w&1)*32;
  int fr = lane&15, fk = (lane>>4)*8;
  f32x4 acc00={0.f,0.f,0.f,0.f}, acc01={0.f,0.f,0.f,0.f};
  f32x4 acc10={0.f,0.f,0.f,0.f}, acc11={0.f,0.f,0.f,0.f};
  const float* ap = A  + (size_t)(m0+srow)*512 + scol;
  const float* bp = We + (size_t)(n0+srow)*512 + scol;
  for (int k0=0; k0<512; k0+=32){
    float4 av0 = *(const float4*)(ap+k0);
    float4 av1 = *(const float4*)(ap+k0+4);
    float4 bv0 = *(const float4*)(bp+k0);
    float4 bv1 = *(const float4*)(bp+k0+4);
    ushort8 va, vb;
    va[0]=f2b(av0.x); va[1]=f2b(av0.y); va[2]=f2b(av0.z); va[3]=f2b(av0.w);
    va[4]=f2b(av1.x); va[5]=f2b(av1.y); va[6]=f2b(av1.z); va[7]=f2b(av1.w);
    vb[0]=f2b(bv0.x); vb[1]=f2b(bv0.y); vb[2]=f2b(bv0.z); vb[3]=f2b(bv0.w);
    vb[4]=f2b(bv1.x); vb[5]=f2b(bv1.y); vb[6]=f2b(bv1.z); vb[7]=f2b(bv1.w);
    __syncthreads();
    *(ushort8*)&As[srow][scol] = va;
    *(ushort8*)&Bs[srow][scol] = vb;
    __syncthreads();
    short8 a0 = *(short8*)&As[wr+fr][fk];
    short8 a1 = *(short8*)&As[wr+16+fr][fk];
    short8 b0 = *(short8*)&Bs[wc+fr][fk];
    short8 b1 = *(short8*)&Bs[wc+16+fr][fk];
    acc00 = __builtin_amdgcn_mfma_f32_16x16x32_bf16(a0,b0,acc00,0,0,0);
    acc01 = __builtin_amdgcn_mfma_f32_16x16x32_bf16(a0,b1,acc01,0,0,0);
    acc10 = __builtin_amdgcn_mfma_f32_16x16x32_bf16(a1,b0,acc10,0,0,0);
    acc11 = __builtin_amdgcn_mfma_f32_16x16x32_bf16(a1,b1,acc11,0,0,0);
  }
  int orow = (lane>>4)*4;
  #pragma unroll
  for (int r=0;r<4;++r){
    Ce[(size_t)(m0+wr+orow+r)*1024    + n0+wc+fr]    = acc00[r];
    Ce[(size_t)(m0+wr+orow+r)*1024    + n0+wc+16+fr] = acc01[r];
    Ce[(size_t)(m0+wr+16+orow+r)*1024 + n0+wc+fr]    = acc10[r];
    Ce[(size_t)(m0+wr+16+orow+r)*1024 + n0+wc+16+fr] = acc11[r];
  }
}

// ---------------- depthwise 3x3 conv + bias + SiLU (expert = blockIdx.z) ----------------
__global__ __launch_bounds__(512) void conv_kernel(
    const float* __restrict__ xz, const float* __restrict__ cw,
    const float* __restrict__ cb, float* __restrict__ xc,
    size_t xzS, size_t xcS)
{
  int e = blockIdx.z;
  const float* xze = xz + (size_t)e*xzS;
  const float* cwe = cw + (size_t)e*4608;
  const float* cbe = cb + (size_t)e*512;
  float* xce = xc + (size_t)e*xcS;
  int t = blockIdx.x, b = blockIdx.y, d = threadIdx.x;
  int h = t/14, w = t - h*14;
  float s = cbe[d];
  #pragma unroll
  for (int dh=-1; dh<=1; ++dh){
    int hh = h+dh; if ((unsigned)hh >= 14u) continue;
    #pragma unroll
    for (int dw=-1; dw<=1; ++dw){
      int ww = w+dw; if ((unsigned)ww >= 14u) continue;
      s = fmaf(xze[((size_t)(b*196 + hh*14+ww))*1024 + d],
               cwe[d*9 + (dh+1)*3 + (dw+1)], s);
    }
  }
  xce[((size_t)(b*196+t))*512 + d] = s * sigmoidf_(s);
}

// ---------------- x_dbl projection (expert = blockIdx.y) ----------------
__global__ __launch_bounds__(256) void proj_kernel(
    const float* __restrict__ xc, const float* __restrict__ xw, float* __restrict__ proj,
    size_t xcS, size_t prS)
{
  int e = blockIdx.y;
  const float* xce = xc + (size_t)e*xcS;
  const float* xwe = xw + (size_t)e*12288;
  float* pre = proj + (size_t)e*prS;
  int wid = threadIdx.x>>6, lane = threadIdx.x&63;
  int m = blockIdx.x*4 + wid;
  const float* xr = xce + (size_t)m*512;
  float xv[8];
  #pragma unroll
  for (int j=0;j<8;++j) xv[j] = xr[j*64+lane];
  #pragma unroll
  for (int kc=0;kc<24;++kc){
    const float* wr = xwe + (size_t)kc*512;
    float a = 0.f;
    #pragma unroll
    for (int j=0;j<8;++j) a = fmaf(xv[j], wr[j*64+lane], a);
    #pragma unroll
    for (int off=32; off; off>>=1) a += __shfl_xor(a,off);
    if (lane==0) pre[(size_t)m*24 + kc] = a;
  }
}

// ---------------- selective scan, thread per (e,b,k,d), atomic merge of 4 directions ----------------
// VALU-optimized: branchless fast softplus via v_exp/v_log, strength-reduced permutation.
__global__ __launch_bounds__(256) void scan_kernel(
    const float* __restrict__ xc, const float* __restrict__ proj,
    const float* __restrict__ Alogs, const float* __restrict__ Dsp,
    const float* __restrict__ dtw, const float* __restrict__ dtb,
    float* __restrict__ ycomb,
    size_t xcS, size_t prS, size_t ycS)
{
  const float LN2 = 0.6931471805599453f;
  int g = blockIdx.x*256 + threadIdx.x;
  int e  = g >> 16;                      // 65536 threads per expert
  int ge = g & 65535;
  int d = ge & 511;
  int k = (ge >> 9) & 3;
  int b = ge >> 11;
  const float* xce = xc + (size_t)e*xcS;
  const float* pre = proj + (size_t)e*prS;
  float* yce = ycomb + (size_t)e*ycS;
  int eo = e*2048;
  float Ak  = -__expf(Alogs[eo + k*512 + d]);
  float Dk  = Dsp[eo + k*512 + d];
  float btk = dtb[eo + k*512 + d];
  const float* wr = dtw + (size_t)e*8192 + ((size_t)(k*512 + d))*4;
  float w0=wr[0], w1=wr[1], w2=wr[2], w3=wr[3];
  float hst = 0.f;
  const float* xcb = xce + (size_t)b*196*512 + d;
  const float* pb  = pre + (size_t)b*196*24 + k*6;
  float* yb = yce + (size_t)b*196*512 + d;

  // strength-reduced permutation: per-direction step + wrap (wave-uniform k)
  int step = (k==0)? 1 : (k==1)? -1 : (k==2)? 14 : -14;
  int t    = (k==0 || k==2)? 0 : 195;

  // prefetch l=0
  float xval = xcb[t*512];
  const float* pp = pb + t*24;
  float p0=pp[0], p1=pp[1], p2=pp[2], p3=pp[3], Bsv=pp[4], Csv=pp[5];

  for (int l=0; l<196; ++l){
    int tn = t + step;
    tn = (tn > 195) ? tn - 195 : tn;
    tn = (tn < 0)   ? tn + 195 : tn;
    float xval_n = xcb[tn*512];
    const float* ppn = pb + tn*24;
    float q0=ppn[0], q1=ppn[1], q2=ppn[2], q3=ppn[3], Bn_=ppn[4], Cn_=ppn[5];

    float dtraw = btk + w0*p0 + w1*p1 + w2*p2 + w3*p3;
    // branchless softplus: max(x,0) + ln2*log2(1+exp(-|x|)), ~2 ulp
    float sp = fmaxf(dtraw, 0.f) + LN2*__log2f(1.0f + __expf(-fabsf(dtraw)));
    float dA = __expf(sp*Ak);
    hst = fmaf(dA, hst, sp*xval*Bsv);
    float y = fmaf(hst, Csv, xval*Dk);
    atomicAdd(&yb[t*512], y);

    t = tn; xval = xval_n;
    p0=q0; p1=q1; p2=q2; p3=q3; Bsv=Bn_; Csv=Cn_;
  }
}

// ---------------- LayerNorm + SiLU(z) gate + comb mix + token-mean accumulate ----------------
template<int NEXP>
__global__ __launch_bounds__(512) void final_kernel(
    const float* __restrict__ ycomb, size_t ycS,
    const float* __restrict__ xz, size_t xzS,
    const float* __restrict__ comb, const float* __restrict__ nw,
    const float* __restrict__ nb, float* __restrict__ out, int e0)
{
  int b = blockIdx.x;
  int t0 = blockIdx.y*28;
  int d = threadIdx.x;
  int wid = d>>6, lane = d&63;
  __shared__ float red[16];
  float wv[NEXP], bv[NEXP];
  #pragma unroll
  for (int i=0;i<NEXP;++i){ wv[i]=nw[(size_t)(e0+i)*512+d]; bv[i]=nb[(size_t)(e0+i)*512+d]; }
  float acc = 0.f;
  for (int ti=0; ti<28; ++ti){
    size_t tok = (size_t)(b*196 + t0 + ti);
    #pragma unroll
    for (int i=0;i<NEXP;++i){
      float v = ycomb[(size_t)i*ycS + tok*512 + d];
      float s=v, q=v*v;
      #pragma unroll
      for (int off=32; off; off>>=1){ s += __shfl_xor(s,off); q += __shfl_xor(q,off); }
      if (lane==0){ red[wid]=s; red[8+wid]=q; }
      __syncthreads();
      float tot=0.f, qt=0.f;
      #pragma unroll
      for (int j=0;j<8;++j){ tot+=red[j]; qt+=red[8+j]; }
      float mu  = tot*(1.f/512.f);
      float var = fmaf(qt, (1.f/512.f), -mu*mu);
      float rs  = rsqrtf(var + 1e-5f);
      float ln  = (v-mu)*rs*wv[i] + bv[i];
      float z   = xz[(size_t)i*xzS + tok*1024 + 512 + d];
      acc = fmaf(comb[tok*4 + e0 + i]*ln, z*sigmoidf_(z), acc);
      __syncthreads();
    }
  }
  atomicAdd(&out[(size_t)b*512+d], acc*(1.f/196.f));
}

extern "C" void kernel_launch(void* const* d_in, const int* in_sizes, int n_in,
                              void* d_out, int out_size, void* d_ws, size_t ws_size,
                              hipStream_t stream)
{
  const float* x    = (const float*)d_in[0];
  const float* eq   = (const float*)d_in[1];
  const float* temp = (const float*)d_in[2];
  const float* ipw  = (const float*)d_in[3];
  const float* cw   = (const float*)d_in[4];
  const float* cb   = (const float*)d_in[5];
  const float* xpw  = (const float*)d_in[6];
  const float* dtw  = (const float*)d_in[7];
  const float* dtb  = (const float*)d_in[8];
  const float* alog = (const float*)d_in[9];
  const float* dsp  = (const float*)d_in[10];
  const float* nw   = (const float*)d_in[11];
  const float* nb   = (const float*)d_in[12];
  float* out = (float*)d_out;

  float* ws      = (float*)d_ws;
  float* comb    = ws;                    // 25088
  float* avgsum  = ws + 25088;            // 4
  float* loadsum = ws + 25092;            // 4

  (void)hipMemsetAsync(avgsum, 0, 8*sizeof(float), stream);
  (void)hipMemsetAsync(d_out, 0, (size_t)out_size*sizeof(float), stream);

  gate_kernel<<<dim3(1568), dim3(256), 0, stream>>>(x, eq, temp, comb, avgsum, loadsum);
  aux_kernel<<<dim3(1), dim3(64), 0, stream>>>(avgsum, loadsum, out + 16384);

  // tier sizes in floats
  const size_t T2 = 52007936ull;                    // batched, f32-staged gemm (~208 MB)
  const size_t T1 = T2 + 1605632ull + 1048576ull;   // + bf16 x and W buffers (~218.6 MB)

  if (ws_size >= T1 * sizeof(float)){
    float* xz = ws + 25600;               // 4 x 6,422,528
    float* xc = xz + 25690112;            // 4 x 3,211,264
    float* pj = xc + 12845056;            // 4 x   150,528
    float* yc = pj + 602112;              // 4 x 3,211,264
    unsigned short* xb = (unsigned short*)(yc + 12845056);   // 3,211,264 ushort
    unsigned short* wb = xb + 3211264;                       // 2,097,152 ushort
    cvt_bf16_kernel<<<dim3(512), dim3(256), 0, stream>>>(x,   xb, 401408);
    cvt_bf16_kernel<<<dim3(512), dim3(256), 0, stream>>>(ipw, wb, 262144);
    gemm_bf16<<<dim3(98,16,4), dim3(256), 0, stream>>>(xb, wb, xz);
    conv_kernel<<<dim3(196,32,4), dim3(512), 0, stream>>>(xz, cw, cb, xc, 6422528, 3211264);
    proj_kernel<<<dim3(1568,4), dim3(256), 0, stream>>>(xc, xpw, pj, 3211264, 150528);
    (void)hipMemsetAsync(yc, 0, 12845056ull*sizeof(float), stream);
    scan_kernel<<<dim3(1024), dim3(256), 0, stream>>>(xc, pj, alog, dsp, dtw, dtb, yc,
                                                      3211264, 150528, 3211264);
    final_kernel<4><<<dim3(32,7), dim3(512), 0, stream>>>(yc, 3211264, xz, 6422528,
                                                          comb, nw, nb, out, 0);
  } else if (ws_size >= T2 * sizeof(float)){
    float* xz = ws + 25600;
    float* xc = xz + 25690112;
    float* pj = xc + 12845056;
    float* yc = pj + 602112;
    gemm_mfma<<<dim3(98,16,4), dim3(256), 0, stream>>>(x, ipw, xz, 524288, 6422528);
    conv_kernel<<<dim3(196,32,4), dim3(512), 0, stream>>>(xz, cw, cb, xc, 6422528, 3211264);
    proj_kernel<<<dim3(1568,4), dim3(256), 0, stream>>>(xc, xpw, pj, 3211264, 150528);
    (void)hipMemsetAsync(yc, 0, 12845056ull*sizeof(float), stream);
    scan_kernel<<<dim3(1024), dim3(256), 0, stream>>>(xc, pj, alog, dsp, dtw, dtb, yc,
                                                      3211264, 150528, 3211264);
    final_kernel<4><<<dim3(32,7), dim3(512), 0, stream>>>(yc, 3211264, xz, 6422528,
                                                          comb, nw, nb, out, 0);
  } else {
    float* xz = ws + 25600;
    float* xc = xz + 6422528;
    float* pj = xc + 3211264;
    float* yc = pj + 150528;
    for (int e=0; e<4; ++e){
      gemm_mfma<<<dim3(98,16,1), dim3(256), 0, stream>>>(x, ipw + (size_t)e*524288, xz, 0, 0);
      conv_kernel<<<dim3(196,32,1), dim3(512), 0, stream>>>(xz, cw + (size_t)e*4608,
                                                            cb + (size_t)e*512, xc, 0, 0);
      proj_kernel<<<dim3(1568,1), dim3(256), 0, stream>>>(xc, xpw + (size_t)e*12288, pj, 0, 0);
      (void)hipMemsetAsync(yc, 0, 3211264ull*sizeof(float), stream);
      scan_kernel<<<dim3(256), dim3(256), 0, stream>>>(xc, pj,
          alog + (size_t)e*2048, dsp + (size_t)e*2048,
          dtw + (size_t)e*8192, dtb + (size_t)e*2048, yc, 0, 0, 0);
      final_kernel<1><<<dim3(32,7), dim3(512), 0, stream>>>(yc, 0, xz, 0, comb, nw, nb, out, e);
    }
  }
}